// Round 12
// baseline (6071.640 us; speedup 1.0000x reference)
//
#include <hip/hip_runtime.h>
#include <hip/hip_bf16.h>
#include <stdint.h>

typedef float f32x4 __attribute__((ext_vector_type(4)));
typedef short short8 __attribute__((ext_vector_type(8)));
typedef long i64;

#define BM 128
#define BN 128
#define BK 64
#define PITCH 72   // LDS row pitch in bf16 elements (144 B)

// f32 -> nearest e4m3fn grid value (as f32). RNE normals via bit trick,
// RNE subnormals via rintf on the uniform 2^-9 grid. Cross-validated vs HW
// v_cvt_pk_fp8_f32 (R1/R3 vs R2/R4 bit-identical).
__device__ __forceinline__ float fp8_round(float x) {
  float ax = __builtin_fabsf(x);
  float sub = rintf(x * 512.f) * 0.001953125f;
  union { float f; uint32_t u; } c; c.f = x;
  uint32_t lsb = (c.u >> 20) & 1u;
  c.u += 0x0007FFFFu + lsb;
  c.u &= 0xFFF00000u;
  return (ax < 0.015625f) ? sub : c.f;
}

// quantize one f32 to e4m3fn grid, return bf16 bits (exact).
__device__ __forceinline__ short q1(float f, float inv_s) {
  float v = fp8_round(fminf(fmaxf(f * inv_s, -448.f), 448.f));
  union { float f; uint32_t u; } c; c.f = v;
  return (short)(c.u >> 16);
}

// round f32 to bf16 (RNE) and return as f32 value
__device__ __forceinline__ float bf16_rne_f32(float f) {
  union { float f; uint32_t u; } c; c.f = f;
  uint32_t lsb = (c.u >> 16) & 1u;
  c.u += 0x7FFFu + lsb;
  c.u &= 0xFFFF0000u;
  return c.f;
}

// C[M,N] = (q(A) @ q(B)^T) * (sx*sw) + bias, bf16 MFMA on fp8-grid values.
// ALL buffers fp32-stored (bf16-valued): inputs verified by R11 oracle
// (band3: E1=0, okx=okw=1, cls=3); OUTPUT fp32 inferred from npz-ratio
// signature 0.469 == input ratio + R8's failure mode.
__global__ __launch_bounds__(256) void gemm_fused_q(
    const float* __restrict__ A, const float* __restrict__ B,
    const float* __restrict__ bias,
    const float* __restrict__ xs, const float* __restrict__ wsc,
    float* __restrict__ C, int M, int N, int K) {
  __shared__ uint8_t sA[BM * PITCH * 2];
  __shared__ uint8_t sB[BN * PITCH * 2];

  const int nbn = N / BN;
  int bid = blockIdx.x;
  { int cpx = gridDim.x >> 3; bid = (bid & 7) * cpx + (bid >> 3); }  // XCD swizzle
  const int bm = bid / nbn;
  const int bn = bid % nbn;

  const int t = threadIdx.x, lane = t & 63, wave = t >> 6;
  const int wm = (wave >> 1) * 64;
  const int wn = (wave & 1) * 64;

  const float invx = 1.0f / xs[0];
  const float invw = 1.0f / wsc[0];

  f32x4 acc[4][4];
#pragma unroll
  for (int i = 0; i < 4; i++)
#pragma unroll
    for (int j = 0; j < 4; j++) acc[i][j] = (f32x4)0.f;

  const float* gA = A + (i64)(bm * BM) * K;
  const float* gB = B + (i64)(bn * BN) * K;

  for (int kt = 0; kt < K; kt += BK) {
    // ---- global load: 8 fp32 per chunk per matrix ----
    f32x4 va[4][2], vb[4][2];
#pragma unroll
    for (int q = 0; q < 4; q++) {
      const int cid = t + (q << 8);        // 0..1023
      const int row = cid >> 3;            // 0..127
      const int c8 = cid & 7;              // 8-elem chunk in row
      const float* pa = gA + (i64)row * K + kt + c8 * 8;
      const float* pb = gB + (i64)row * K + kt + c8 * 8;
      va[q][0] = *(const f32x4*)pa;  va[q][1] = *(const f32x4*)(pa + 4);
      vb[q][0] = *(const f32x4*)pb;  vb[q][1] = *(const f32x4*)(pb + 4);
    }
    // ---- quantize to fp8 grid, pack as bf16x8 (exact) ----
    short8 qa[4], qb[4];
#pragma unroll
    for (int q = 0; q < 4; q++) {
#pragma unroll
      for (int e = 0; e < 4; e++) {
        qa[q][e]     = q1(va[q][0][e], invx);
        qa[q][4 + e] = q1(va[q][1][e], invx);
        qb[q][e]     = q1(vb[q][0][e], invw);
        qb[q][4 + e] = q1(vb[q][1][e], invw);
      }
    }

    __syncthreads();   // previous iteration's LDS reads complete
#pragma unroll
    for (int q = 0; q < 4; q++) {
      const int cid = t + (q << 8);
      const int row = cid >> 3;
      const int c8 = cid & 7;
      *(short8*)(sA + (row * PITCH + c8 * 8) * 2) = qa[q];
      *(short8*)(sB + (row * PITCH + c8 * 8) * 2) = qb[q];
    }
    __syncthreads();   // tiles visible

    // ---- MFMA: 2 K-substeps of 32 ----
#pragma unroll
    for (int ks = 0; ks < 2; ks++) {
      const int ke = ks * 32 + ((lane >> 4) << 3);
      short8 af[4], bf_[4];
#pragma unroll
      for (int i = 0; i < 4; i++) {
        af[i]  = *(const short8*)(sA + ((wm + i * 16 + (lane & 15)) * PITCH + ke) * 2);
        bf_[i] = *(const short8*)(sB + ((wn + i * 16 + (lane & 15)) * PITCH + ke) * 2);
      }
#pragma unroll
      for (int i = 0; i < 4; i++)
#pragma unroll
        for (int j = 0; j < 4; j++)
          acc[i][j] = __builtin_amdgcn_mfma_f32_16x16x32_bf16(
              af[i], bf_[j], acc[i][j], 0, 0, 0);
    }
  }

  // ---- epilogue: bf16_rne(acc*(sx*sw) + bias) stored as FP32 ----
  const float sc = xs[0] * wsc[0];
  const int col0 = bn * BN + wn + (lane & 15);
  const int row0 = bm * BM + wm + ((lane >> 4) << 2);
#pragma unroll
  for (int j = 0; j < 4; j++) {
    const int col = col0 + j * 16;
    const float bv = bias[col];
#pragma unroll
    for (int i = 0; i < 4; i++) {
      const int row = row0 + i * 16;
#pragma unroll
      for (int r = 0; r < 4; r++) {
        C[(i64)(row + r) * N + col] = bf16_rne_f32(acc[i][j][r] * sc + bv);
      }
    }
  }
}

extern "C" void kernel_launch(void* const* d_in, const int* in_sizes, int n_in,
                              void* d_out, int out_size, void* d_ws, size_t ws_size,
                              hipStream_t stream) {
  // Verified by R11 oracle: declared order, element counts, fp32 storage.
  const float* x = (const float*)d_in[0];
  const float* w = (const float*)d_in[1];
  const float* bias = (const float*)d_in[2];
  const float* x_scale = (const float*)d_in[3];
  const float* w_scale = (const float*)d_in[4];
  // d_in[5] = gy_scale (unused in forward)

  const int N = in_sizes[2];
  const int K = in_sizes[1] / N;
  const int M = in_sizes[0] / K;

  dim3 grid((M / BM) * (N / BN));
  gemm_fused_q<<<grid, 256, 0, stream>>>(
      x, w, bias, x_scale, w_scale, (float*)d_out, M, N, K);
}

// Round 13
// 1420.520 us; speedup vs baseline: 4.2742x; 4.2742x over previous
//
#include <hip/hip_runtime.h>
#include <hip/hip_bf16.h>
#include <stdint.h>

typedef float f32x4 __attribute__((ext_vector_type(4)));
typedef long i64;

#define BM 128
#define BN 128
#define BKB 64   // K-bytes per tile step (fp8: 64 elements)

// ---------------- pre-quant: fp32 (bf16-valued) -> fp8 e4m3fn ----------------
// Each thread: 16 fp32 in (64 B) -> 16 fp8 out (16 B). HW RNE+sat cvt,
// cross-validated vs soft RNE (R1<->R2 bit-identical through a full GEMM).
__global__ __launch_bounds__(256) void quant_fp8_from_f32(
    const float* __restrict__ in, const float* __restrict__ scale,
    uint8_t* __restrict__ out, int n16) {
  const int i = blockIdx.x * blockDim.x + threadIdx.x;
  if (i >= n16) return;
  const float inv_s = 1.0f / scale[0];   // scale==1.0 in this benchmark
  const float* p = in + (i64)i * 16;
  f32x4 v[4];
  v[0] = *(const f32x4*)p;
  v[1] = *(const f32x4*)(p + 4);
  v[2] = *(const f32x4*)(p + 8);
  v[3] = *(const f32x4*)(p + 12);
  uint32_t w[4];
#pragma unroll
  for (int q = 0; q < 4; q++) {
    float f0 = fminf(fmaxf(v[q][0] * inv_s, -448.f), 448.f);
    float f1 = fminf(fmaxf(v[q][1] * inv_s, -448.f), 448.f);
    float f2 = fminf(fmaxf(v[q][2] * inv_s, -448.f), 448.f);
    float f3 = fminf(fmaxf(v[q][3] * inv_s, -448.f), 448.f);
    int r = 0;
    r = __builtin_amdgcn_cvt_pk_fp8_f32(f0, f1, r, false);
    r = __builtin_amdgcn_cvt_pk_fp8_f32(f2, f3, r, true);
    w[q] = (uint32_t)r;
  }
  ((uint4*)out)[i] = make_uint4(w[0], w[1], w[2], w[3]);
}

// ---------------- async global->LDS, 16B per lane ----------------
__device__ __forceinline__ void gload_lds16(const void* g, void* l) {
  __builtin_amdgcn_global_load_lds(
      (const __attribute__((address_space(1))) uint32_t*)g,
      (__attribute__((address_space(3))) uint32_t*)l, 16, 0, 0);
}

// round f32 to bf16 (RNE) and return as f32 value
__device__ __forceinline__ float bf16_rne_f32(float f) {
  union { float f; uint32_t u; } c; c.f = f;
  uint32_t lsb = (c.u >> 16) & 1u;
  c.u += 0x7FFFu + lsb;
  c.u &= 0xFFFF0000u;
  return c.f;
}

// ---------------- fp8 GEMM: C[M,N] = Aq[M,K]*Bq[N,K]^T * sc + bias ----------
// 128x128 tile, 4 waves (2x2 of 64x64), BK=64 fp8 elems, 16x16x32 fp8 MFMA.
// LDS [128 rows][64 B]; 16B-chunk XOR swizzle chunk' = chunk ^ (row&3) applied
// via pre-swizzled GLOBAL source (LDS dest stays linear for global_load_lds).
// Core functionally verified (R1 == R2 bit-identity through full GEMM).
__global__ __launch_bounds__(256) void gemm_fp8(
    const uint8_t* __restrict__ Aq, const uint8_t* __restrict__ Bq,
    const float* __restrict__ bias,
    const float* __restrict__ xs, const float* __restrict__ wsc,
    float* __restrict__ C, int M, int N, int K) {
  __shared__ uint8_t sA[BM * BKB];
  __shared__ uint8_t sB[BN * BKB];

  const int nbn = N / BN;
  int bid = blockIdx.x;
  { int cpx = gridDim.x >> 3; bid = (bid & 7) * cpx + (bid >> 3); }  // XCD swizzle
  const int bm = bid / nbn;
  const int bn = bid % nbn;

  const int t = threadIdx.x, lane = t & 63, wave = t >> 6;
  const int wm = (wave >> 1) * 64;
  const int wn = (wave & 1) * 64;

  f32x4 acc[4][4];
#pragma unroll
  for (int i = 0; i < 4; i++)
#pragma unroll
    for (int j = 0; j < 4; j++) acc[i][j] = (f32x4)0.f;

  // staging geometry: thread t covers 16B chunk c16=t&3 of row t/4 (+64 for j=1)
  const int srow = t >> 2;
  const int c16 = t & 3;
  const uint8_t* gA = Aq + (i64)(bm * BM) * K;
  const uint8_t* gB = Bq + (i64)(bn * BN) * K;

  for (int kt = 0; kt < K; kt += BKB) {
#pragma unroll
    for (int j = 0; j < 2; j++) {
      const int row = srow + j * 64;
      const i64 src = (i64)row * K + kt + ((c16 ^ (row & 3)) << 4);
      gload_lds16(gA + src, sA + t * 16 + j * 4096);
      gload_lds16(gB + src, sB + t * 16 + j * 4096);
    }
    __syncthreads();   // drains vmcnt before barrier

#pragma unroll
    for (int ks = 0; ks < 2; ks++) {
      const int koff = ks * 32 + ((lane >> 4) << 3);  // this lane's k byte offset
      i64 a_f[4], b_f[4];
#pragma unroll
      for (int i = 0; i < 4; i++) {
        const int ra = wm + i * 16 + (lane & 15);
        const int aaddr = ra * 64 + (((koff >> 4) ^ (ra & 3)) << 4) + (koff & 15);
        a_f[i] = *(const i64*)(sA + aaddr);
        const int rb = wn + i * 16 + (lane & 15);
        const int baddr = rb * 64 + (((koff >> 4) ^ (rb & 3)) << 4) + (koff & 15);
        b_f[i] = *(const i64*)(sB + baddr);
      }
#pragma unroll
      for (int i = 0; i < 4; i++)
#pragma unroll
        for (int j = 0; j < 4; j++)
          acc[i][j] = __builtin_amdgcn_mfma_f32_16x16x32_fp8_fp8(
              a_f[i], b_f[j], acc[i][j], 0, 0, 0);
    }
    __syncthreads();
  }

  // epilogue: bf16_rne(acc*(sx*sw) + bias) stored as FP32 (R12-verified)
  const float sc = xs[0] * wsc[0];
  const int col0 = bn * BN + wn + (lane & 15);
  const int row0 = bm * BM + wm + ((lane >> 4) << 2);
#pragma unroll
  for (int j = 0; j < 4; j++) {
    const int col = col0 + j * 16;
    const float bv = bias[col];
#pragma unroll
    for (int i = 0; i < 4; i++) {
      const int row = row0 + i * 16;
#pragma unroll
      for (int r = 0; r < 4; r++) {
        C[(i64)(row + r) * N + col] = bf16_rne_f32(acc[i][j][r] * sc + bv);
      }
    }
  }
}

extern "C" void kernel_launch(void* const* d_in, const int* in_sizes, int n_in,
                              void* d_out, int out_size, void* d_ws, size_t ws_size,
                              hipStream_t stream) {
  // Verified I/O model (R11 oracle + R12 pass): declared order, element
  // counts, ALL buffers fp32-stored bf16-valued, output fp32.
  const float* x = (const float*)d_in[0];
  const float* w = (const float*)d_in[1];
  const float* bias = (const float*)d_in[2];
  const float* x_scale = (const float*)d_in[3];
  const float* w_scale = (const float*)d_in[4];
  // d_in[5] = gy_scale (unused in forward)

  const int N = in_sizes[2];
  const int K = in_sizes[1] / N;
  const int M = in_sizes[0] / K;

  uint8_t* xq = (uint8_t*)d_ws;                     // M*K = 32 MB
  uint8_t* wq = (uint8_t*)d_ws + (size_t)M * K;     // N*K = 64 MB
  // (ws capacity validated empirically: R1 used this exact layout and
  //  produced results bit-identical to the no-ws R2 path.)

  {
    const int n16 = (M * K) / 16;
    quant_fp8_from_f32<<<(n16 + 255) / 256, 256, 0, stream>>>(x, x_scale, xq, n16);
  }
  {
    const int n16 = (int)(((i64)N * K) / 16);
    quant_fp8_from_f32<<<(n16 + 255) / 256, 256, 0, stream>>>(w, w_scale, wq, n16);
  }

  dim3 grid((M / BM) * (N / BN));
  gemm_fp8<<<grid, 256, 0, stream>>>(
      xq, wq, bias, x_scale, w_scale, (float*)d_out, M, N, K);
}

// Round 14
// 1092.567 us; speedup vs baseline: 5.5572x; 1.3002x over previous
//
#include <hip/hip_runtime.h>
#include <hip/hip_bf16.h>
#include <stdint.h>

typedef float f32x4 __attribute__((ext_vector_type(4)));
typedef long i64;
typedef long i64x2 __attribute__((ext_vector_type(2)));

#define BM 128
#define BN 128
#define BKB 64   // K-bytes per tile step (fp8: 64 elements)

// ---------------- pre-quant + layout permute --------------------------------
// fp32 (bf16-valued) -> fp8 e4m3fn, written in MFMA-fragment-interleaved
// order: within each 64-elem K-group, 16B block b = [k: b*8..b*8+8 | k:
// 32+b*8..32+b*8+8]. One ds_read_b128 then feeds both K=32 substeps.
__global__ __launch_bounds__(256) void quant_fp8_perm(
    const float* __restrict__ in, const float* __restrict__ scale,
    uint8_t* __restrict__ out, int n16) {
  const int i = blockIdx.x * blockDim.x + threadIdx.x;
  if (i >= n16) return;
  const float inv_s = 1.0f / scale[0];
  const i64 f = (i64)i * 16;            // flat fp8 element index of this block
  const i64 base = f & ~(i64)63;        // start of 64-elem K-group (K%64==0)
  const int b = (int)((f >> 4) & 3);    // block index within group
  const float* p0 = in + base + b * 8;        // ks0 piece
  const float* p1 = in + base + 32 + b * 8;   // ks1 piece
  f32x4 v[4];
  v[0] = *(const f32x4*)p0;  v[1] = *(const f32x4*)(p0 + 4);
  v[2] = *(const f32x4*)p1;  v[3] = *(const f32x4*)(p1 + 4);
  uint32_t w[4];
#pragma unroll
  for (int q = 0; q < 4; q++) {
    float f0 = fminf(fmaxf(v[q][0] * inv_s, -448.f), 448.f);
    float f1 = fminf(fmaxf(v[q][1] * inv_s, -448.f), 448.f);
    float f2 = fminf(fmaxf(v[q][2] * inv_s, -448.f), 448.f);
    float f3 = fminf(fmaxf(v[q][3] * inv_s, -448.f), 448.f);
    int r = 0;
    r = __builtin_amdgcn_cvt_pk_fp8_f32(f0, f1, r, false);
    r = __builtin_amdgcn_cvt_pk_fp8_f32(f2, f3, r, true);
    w[q] = (uint32_t)r;
  }
  ((uint4*)out)[i] = make_uint4(w[0], w[1], w[2], w[3]);
}

// ---------------- async global->LDS, 16B per lane ----------------
__device__ __forceinline__ void gload_lds16(const void* g, void* l) {
  __builtin_amdgcn_global_load_lds(
      (const __attribute__((address_space(1))) uint32_t*)g,
      (__attribute__((address_space(3))) uint32_t*)l, 16, 0, 0);
}

// round f32 to bf16 (RNE) and return as f32 value
__device__ __forceinline__ float bf16_rne_f32(float f) {
  union { float f; uint32_t u; } c; c.f = f;
  uint32_t lsb = (c.u >> 16) & 1u;
  c.u += 0x7FFFu + lsb;
  c.u &= 0xFFFF0000u;
  return c.f;
}

// ---------------- fp8 GEMM: C[M,N] = Aq[M,K]*Bq[N,K]^T * sc + bias ----------
// 128x128 tile, 4 waves (2x2 of 64x64), BK=64 fp8 elems, 16x16x32 fp8 MFMA.
// LDS [128 rows][64 B]; 16B-chunk XOR swizzle chunk' = chunk ^ ((row>>1)&3)
// -- the >>1 decouples swizzle bits from the bank-parity bit (row&1), giving
// floor-optimal 2-per-phase bank load (R13's row&3 variant was 2x over floor).
// Swizzle applied via pre-swizzled GLOBAL source; LDS dest stays linear.
__global__ __launch_bounds__(256) void gemm_fp8(
    const uint8_t* __restrict__ Aq, const uint8_t* __restrict__ Bq,
    const float* __restrict__ bias,
    const float* __restrict__ xs, const float* __restrict__ wsc,
    float* __restrict__ C, int M, int N, int K) {
  __shared__ uint8_t sA[BM * BKB];
  __shared__ uint8_t sB[BN * BKB];

  const int nbn = N / BN;
  int bid = blockIdx.x;
  { int cpx = gridDim.x >> 3; bid = (bid & 7) * cpx + (bid >> 3); }  // XCD swizzle
  const int bm = bid / nbn;
  const int bn = bid % nbn;

  const int t = threadIdx.x, lane = t & 63, wave = t >> 6;
  const int wm = (wave >> 1) * 64;
  const int wn = (wave & 1) * 64;
  const int g = lane >> 4;          // k-fragment group

  f32x4 acc[4][4];
#pragma unroll
  for (int i = 0; i < 4; i++)
#pragma unroll
    for (int j = 0; j < 4; j++) acc[i][j] = (f32x4)0.f;

  // ---- staging geometry: thread t covers 16B block (t&3) of row t/4 (+64) ----
  const int srow = t >> 2;
  const int c16 = t & 3;
  // pre-swizzled global source offsets (constant part; add kt per iter)
  i64 srcA0, srcA1;
  {
    const int r0 = srow, r1 = srow + 64;
    srcA0 = (i64)r0 * K + ((c16 ^ ((r0 >> 1) & 3)) << 4);
    srcA1 = (i64)r1 * K + ((c16 ^ ((r1 >> 1) & 3)) << 4);
  }
  const uint8_t* gA = Aq + (i64)(bm * BM) * K;
  const uint8_t* gB = Bq + (i64)(bn * BN) * K;
  uint8_t* ldsA0 = sA + t * 16;
  uint8_t* ldsA1 = sA + t * 16 + 4096;
  uint8_t* ldsB0 = sB + t * 16;
  uint8_t* ldsB1 = sB + t * 16 + 4096;

  // ---- fragment read addresses (loop-invariant, hoisted) ----
  int aaddr[4], baddr[4];
#pragma unroll
  for (int i = 0; i < 4; i++) {
    const int ra = wm + i * 16 + (lane & 15);
    aaddr[i] = ra * 64 + ((g ^ ((ra >> 1) & 3)) << 4);
    const int rb = wn + i * 16 + (lane & 15);
    baddr[i] = rb * 64 + ((g ^ ((rb >> 1) & 3)) << 4);
  }

  for (int kt = 0; kt < K; kt += BKB) {
    gload_lds16(gA + srcA0 + kt, ldsA0);
    gload_lds16(gA + srcA1 + kt, ldsA1);
    gload_lds16(gB + srcA0 + kt, ldsB0);   // same (row,chunk) geometry for B
    gload_lds16(gB + srcA1 + kt, ldsB1);
    __syncthreads();   // drains vmcnt before barrier

    i64x2 a2[4], b2[4];
#pragma unroll
    for (int i = 0; i < 4; i++) {
      a2[i] = *(const i64x2*)(sA + aaddr[i]);
      b2[i] = *(const i64x2*)(sB + baddr[i]);
    }
#pragma unroll
    for (int ks = 0; ks < 2; ks++)
#pragma unroll
      for (int i = 0; i < 4; i++)
#pragma unroll
        for (int j = 0; j < 4; j++)
          acc[i][j] = __builtin_amdgcn_mfma_f32_16x16x32_fp8_fp8(
              a2[i][ks], b2[j][ks], acc[i][j], 0, 0, 0);
    __syncthreads();
  }

  // epilogue: bf16_rne(acc*(sx*sw) + bias) stored as FP32 (R12-verified)
  const float sc = xs[0] * wsc[0];
  const int col0 = bn * BN + wn + (lane & 15);
  const int row0 = bm * BM + wm + (g << 2);
#pragma unroll
  for (int j = 0; j < 4; j++) {
    const int col = col0 + j * 16;
    const float bv = bias[col];
#pragma unroll
    for (int i = 0; i < 4; i++) {
      const int row = row0 + i * 16;
#pragma unroll
      for (int r = 0; r < 4; r++) {
        C[(i64)(row + r) * N + col] = bf16_rne_f32(acc[i][j][r] * sc + bv);
      }
    }
  }
}

extern "C" void kernel_launch(void* const* d_in, const int* in_sizes, int n_in,
                              void* d_out, int out_size, void* d_ws, size_t ws_size,
                              hipStream_t stream) {
  // Verified I/O model (R11 oracle + R12/R13 pass): declared order, element
  // counts, ALL buffers fp32-stored bf16-valued, output fp32.
  const float* x = (const float*)d_in[0];
  const float* w = (const float*)d_in[1];
  const float* bias = (const float*)d_in[2];
  const float* x_scale = (const float*)d_in[3];
  const float* w_scale = (const float*)d_in[4];

  const int N = in_sizes[2];
  const int K = in_sizes[1] / N;
  const int M = in_sizes[0] / K;

  uint8_t* xq = (uint8_t*)d_ws;                     // M*K = 32 MB
  uint8_t* wq = (uint8_t*)d_ws + (size_t)M * K;     // N*K = 64 MB

  {
    const int n16 = (M * K) / 16;
    quant_fp8_perm<<<(n16 + 255) / 256, 256, 0, stream>>>(x, x_scale, xq, n16);
  }
  {
    const int n16 = (int)(((i64)N * K) / 16);
    quant_fp8_perm<<<(n16 + 255) / 256, 256, 0, stream>>>(w, w_scale, wq, n16);
  }

  dim3 grid((M / BM) * (N / BN));
  gemm_fp8<<<grid, 256, 0, stream>>>(
      xq, wq, bias, x_scale, w_scale, (float*)d_out, M, N, K);
}

// Round 15
// 934.924 us; speedup vs baseline: 6.4943x; 1.1686x over previous
//
#include <hip/hip_runtime.h>
#include <hip/hip_bf16.h>
#include <stdint.h>

typedef float f32x4 __attribute__((ext_vector_type(4)));
typedef float f32x16 __attribute__((ext_vector_type(16)));
typedef int i32x4 __attribute__((ext_vector_type(4)));
typedef int i32x8 __attribute__((ext_vector_type(8)));
typedef long i64;

#define BM 128
#define BN 128
#define BKB 64   // K elements (=bytes, fp8) per tile step

// ---------------- pre-quant: fp32 (bf16-valued) -> fp8 e4m3fn, LINEAR -------
__global__ __launch_bounds__(256) void quant_fp8_from_f32(
    const float* __restrict__ in, const float* __restrict__ scale,
    uint8_t* __restrict__ out, int n16) {
  const int i = blockIdx.x * blockDim.x + threadIdx.x;
  if (i >= n16) return;
  const float inv_s = 1.0f / scale[0];
  const float* p = in + (i64)i * 16;
  f32x4 v[4];
  v[0] = *(const f32x4*)p;
  v[1] = *(const f32x4*)(p + 4);
  v[2] = *(const f32x4*)(p + 8);
  v[3] = *(const f32x4*)(p + 12);
  uint32_t w[4];
#pragma unroll
  for (int q = 0; q < 4; q++) {
    float f0 = fminf(fmaxf(v[q][0] * inv_s, -448.f), 448.f);
    float f1 = fminf(fmaxf(v[q][1] * inv_s, -448.f), 448.f);
    float f2 = fminf(fmaxf(v[q][2] * inv_s, -448.f), 448.f);
    float f3 = fminf(fmaxf(v[q][3] * inv_s, -448.f), 448.f);
    int r = 0;
    r = __builtin_amdgcn_cvt_pk_fp8_f32(f0, f1, r, false);
    r = __builtin_amdgcn_cvt_pk_fp8_f32(f2, f3, r, true);
    w[q] = (uint32_t)r;
  }
  ((uint4*)out)[i] = make_uint4(w[0], w[1], w[2], w[3]);
}

// ---------------- async global->LDS, 16B per lane ----------------
__device__ __forceinline__ void gload_lds16(const void* g, void* l) {
  __builtin_amdgcn_global_load_lds(
      (const __attribute__((address_space(1))) uint32_t*)g,
      (__attribute__((address_space(3))) uint32_t*)l, 16, 0, 0);
}

// round f32 to bf16 (RNE), return as f32 value
__device__ __forceinline__ float bf16_rne_f32(float f) {
  union { float f; uint32_t u; } c; c.f = f;
  uint32_t lsb = (c.u >> 16) & 1u;
  c.u += 0x7FFFu + lsb;
  c.u &= 0xFFFF0000u;
  return c.f;
}

// ---------------- fp8 GEMM via MX-scaled 32x32x64 MFMA (scales = 1.0) -------
// C[M,N] = Aq[M,K]*Bq[N,K]^T * sc + bias. 128x128 tile, 4 waves (2x2 of
// 64x64), each wave 2x2 of 32x32x64 mfma_scale_f32 (fp8 fmt, e8m0 scale 127
// = 1.0 -> bit-identical to non-scaled fp8, 2.3x the MFMA rate).
// LDS [128 rows][64 B], 16B-chunk XOR swizzle chunk' = chunk ^ ((row>>1)&3),
// applied via pre-swizzled GLOBAL source (linear LDS dest, R14-verified 0
// bank conflicts). Fragment reads: lane (g=lane>>5) reads chunks {2g,2g+1}
// of row (wm+i*32+(lane&31)) -> k = g*32..g*32+31, natural k-order.
__global__ __launch_bounds__(256) void gemm_fp8_mx(
    const uint8_t* __restrict__ Aq, const uint8_t* __restrict__ Bq,
    const float* __restrict__ bias,
    const float* __restrict__ xs, const float* __restrict__ wsc,
    float* __restrict__ C, int M, int N, int K) {
  __shared__ uint8_t sA[BM * BKB];
  __shared__ uint8_t sB[BN * BKB];

  const int nbn = N / BN;
  int bid = blockIdx.x;
  { int cpx = gridDim.x >> 3; bid = (bid & 7) * cpx + (bid >> 3); }  // XCD swizzle
  const int bm = bid / nbn;
  const int bn = bid % nbn;

  const int t = threadIdx.x, lane = t & 63, wave = t >> 6;
  const int wm = (wave >> 1) * 64;
  const int wn = (wave & 1) * 64;
  const int g = lane >> 5;          // K-half group (0: k0-31, 1: k32-63)
  const int r31 = lane & 31;

  f32x16 acc[2][2];
#pragma unroll
  for (int i = 0; i < 2; i++)
#pragma unroll
    for (int j = 0; j < 2; j++) acc[i][j] = (f32x16)0.f;

  // ---- staging geometry: thread t stages 16B chunk (t&3) of rows t/4, t/4+64
  const int srow = t >> 2;
  const int c16 = t & 3;
  i64 src0, src1;
  {
    const int r0 = srow, r1 = srow + 64;
    src0 = (i64)r0 * K + ((c16 ^ ((r0 >> 1) & 3)) << 4);
    src1 = (i64)r1 * K + ((c16 ^ ((r1 >> 1) & 3)) << 4);
  }
  const uint8_t* gA = Aq + (i64)(bm * BM) * K;
  const uint8_t* gB = Bq + (i64)(bn * BN) * K;
  uint8_t* ldsA0 = sA + t * 16;
  uint8_t* ldsA1 = sA + t * 16 + 4096;
  uint8_t* ldsB0 = sB + t * 16;
  uint8_t* ldsB1 = sB + t * 16 + 4096;

  // ---- fragment read addresses (hoisted): [frag][chunk-half]
  int aoff[2][2], boff[2][2];
#pragma unroll
  for (int i = 0; i < 2; i++) {
    const int ra = wm + i * 32 + r31;
    const int swa = (ra >> 1) & 3;
    aoff[i][0] = ra * 64 + (((2 * g + 0) ^ swa) << 4);
    aoff[i][1] = ra * 64 + (((2 * g + 1) ^ swa) << 4);
    const int rb = wn + i * 32 + r31;
    const int swb = (rb >> 1) & 3;
    boff[i][0] = rb * 64 + (((2 * g + 0) ^ swb) << 4);
    boff[i][1] = rb * 64 + (((2 * g + 1) ^ swb) << 4);
  }

  for (int kt = 0; kt < K; kt += BKB) {
    gload_lds16(gA + src0 + kt, ldsA0);
    gload_lds16(gA + src1 + kt, ldsA1);
    gload_lds16(gB + src0 + kt, ldsB0);
    gload_lds16(gB + src1 + kt, ldsB1);
    __syncthreads();   // compiler drains vmcnt before barrier

    union { i32x4 h[2]; i32x8 v; } ua[2], ub[2];
#pragma unroll
    for (int i = 0; i < 2; i++) {
      ua[i].h[0] = *(const i32x4*)(sA + aoff[i][0]);
      ua[i].h[1] = *(const i32x4*)(sA + aoff[i][1]);
      ub[i].h[0] = *(const i32x4*)(sB + boff[i][0]);
      ub[i].h[1] = *(const i32x4*)(sB + boff[i][1]);
    }
#pragma unroll
    for (int i = 0; i < 2; i++)
#pragma unroll
      for (int j = 0; j < 2; j++)
        acc[i][j] = __builtin_amdgcn_mfma_scale_f32_32x32x64_f8f6f4(
            ua[i].v, ub[j].v, acc[i][j],
            0, 0,          // cbsz=fp8(e4m3), blgp=fp8(e4m3)
            0, 127,        // opsel_a, scale_a = e8m0 1.0
            0, 127);       // opsel_b, scale_b = e8m0 1.0
    __syncthreads();
  }

  // ---- epilogue: bf16_rne(acc*(sx*sw) + bias) stored as FP32 -------------
  // 32x32 C/D layout (m74/m101): col = lane&31, row = (reg&3)+8*(reg>>2)+4*g
  const float sc = xs[0] * wsc[0];
#pragma unroll
  for (int j = 0; j < 2; j++) {
    const int col = bn * BN + wn + j * 32 + r31;
    const float bv = bias[col];
#pragma unroll
    for (int i = 0; i < 2; i++) {
      const int rowbase = bm * BM + wm + i * 32 + 4 * g;
#pragma unroll
      for (int reg = 0; reg < 16; reg++) {
        const int row = rowbase + (reg & 3) + 8 * (reg >> 2);
        C[(i64)row * N + col] = bf16_rne_f32(acc[i][j][reg] * sc + bv);
      }
    }
  }
}

extern "C" void kernel_launch(void* const* d_in, const int* in_sizes, int n_in,
                              void* d_out, int out_size, void* d_ws, size_t ws_size,
                              hipStream_t stream) {
  // Verified I/O model (R11 oracle + R12-R14 passes): declared order, element
  // counts, ALL buffers fp32-stored bf16-valued, output fp32.
  const float* x = (const float*)d_in[0];
  const float* w = (const float*)d_in[1];
  const float* bias = (const float*)d_in[2];
  const float* x_scale = (const float*)d_in[3];
  const float* w_scale = (const float*)d_in[4];

  const int N = in_sizes[2];
  const int K = in_sizes[1] / N;
  const int M = in_sizes[0] / K;

  uint8_t* xq = (uint8_t*)d_ws;                     // M*K = 32 MB
  uint8_t* wq = (uint8_t*)d_ws + (size_t)M * K;     // N*K = 64 MB

  {
    const int n16 = (M * K) / 16;
    quant_fp8_from_f32<<<(n16 + 255) / 256, 256, 0, stream>>>(x, x_scale, xq, n16);
  }
  {
    const int n16 = (int)(((i64)N * K) / 16);
    quant_fp8_from_f32<<<(n16 + 255) / 256, 256, 0, stream>>>(w, w_scale, wq, n16);
  }

  dim3 grid((M / BM) * (N / BN));
  gemm_fp8_mx<<<grid, 256, 0, stream>>>(
      xq, wq, bias, x_scale, w_scale, (float*)d_out, M, N, K);
}